// Round 4
// baseline (1198.784 us; speedup 1.0000x reference)
//
#include <hip/hip_runtime.h>
#include <hip/hip_bf16.h>
#include <cmath>

// Problem constants
#define L_SEQ  1024
#define BATCH  16
#define NOUT   512          // n
#define DIN    1024         // 2n = layer input dim = GEMM K
#define NBIG   3072         // 6n = GEMM N
#define NLAYERS 4
#define NTOK   (L_SEQ * BATCH)   // 16384 = GEMM M
#define NCHAIN 16384             // B * 2 * n independent scan chains
#define SEG    32                // segments per chain
#define SEGLEN (L_SEQ / SEG)     // 32 steps per segment

typedef __attribute__((ext_vector_type(8))) short bf16x8;
typedef __attribute__((ext_vector_type(4))) float f32x4;

__device__ __forceinline__ unsigned short f2bf(float f) {
    unsigned x = __float_as_uint(f);
    unsigned r = (x + 0x7fffu + ((x >> 16) & 1u)) >> 16;   // RNE
    return (unsigned short)r;
}
__device__ __forceinline__ float bf2f(unsigned short hv) {
    return __uint_as_float((unsigned)hv << 16);
}
__device__ __forceinline__ float sigmf(float v) {
    return 1.f / (1.f + __expf(-v));
}
__device__ __forceinline__ void async16(const void* g, const void* l) {
    __builtin_amdgcn_global_load_lds(
        (const __attribute__((address_space(1))) unsigned int*)g,
        (__attribute__((address_space(3))) unsigned int*)l, 16, 0, 0);
}

// ---------------- W convert + transpose: W(1024,3072) f32 -> Wt(3072,1024) bf16 ----------------
__global__ __launch_bounds__(256)
void transpose_w(const float* __restrict__ Ws, unsigned short* __restrict__ Wt) {
    __shared__ float tile[32][33];
    int l = blockIdx.z;
    const float* W = Ws + (size_t)l * DIN * NBIG;
    unsigned short* Wo = Wt + (size_t)l * NBIG * DIN;
    int n0 = blockIdx.x * 32, k0 = blockIdx.y * 32;
    int tx = threadIdx.x & 31, ty = threadIdx.x >> 5;
    #pragma unroll
    for (int i = 0; i < 4; i++)
        tile[ty + 8 * i][tx] = W[(size_t)(k0 + ty + 8 * i) * NBIG + n0 + tx];
    __syncthreads();
    #pragma unroll
    for (int i = 0; i < 4; i++)
        Wo[(size_t)(n0 + ty + 8 * i) * DIN + k0 + tx] = f2bf(tile[tx][ty + 8 * i]);
}

// ---------------- embedding gather: write x fp32 + xbf bf16 ----------------
__global__ void embed_kernel(const int* __restrict__ tok,
                             const float* __restrict__ emb,
                             float* __restrict__ x,
                             unsigned short* __restrict__ xbf) {
    int t = blockIdx.x;
    int row = tok[t];
    float4 v = ((const float4*)(emb + (size_t)row * DIN))[threadIdx.x];
    ((float4*)(x + (size_t)t * DIN))[threadIdx.x] = v;
    ushort4 h;
    h.x = f2bf(v.x); h.y = f2bf(v.y); h.z = f2bf(v.z); h.w = f2bf(v.w);
    ((ushort4*)(xbf + (size_t)t * DIN))[threadIdx.x] = h;
}

// ---------------- bf16 MFMA GEMM: u = x @ W ----------------
// PERSISTENT version: grid 256 blocks; each block owns one 256-row M-panel and
// processes 3 N-tiles (c=0..2). 8-phase K-loop (unchanged schedule, verified
// r3) with dual-bg register set (no P4/P8 re-read). Tile transition:
//   K-loop(c-1) done -> acc->bf16 ds_write to LDS (quad-XOR swizzle, 2-way
//   free) -> bar -> 16x ds_read_b128 -> bar -> prologue stages(c) ->
//   16x dwordx4 coalesced stores(c-1) -> vmcnt(22) [forces tile0's 8 loads,
//   leaves 6 loads+16 stores draining into the K-loop] -> bar -> K-loop(c).
// acc re-zero after lgkmcnt(0) on ds_writes (no store-WAR drain).
// XCD map: xcd=bid&7 gets M-tiles [xcd*8,xcd*8+8) x p in 0..3; A-panels
// 8x512KB = 4MB = one XCD L2; N-tiles of block = {3p,3p+1,3p+2} (each N-tile
// lies in ONE u-plane since plane width 512 = 2 tiles).

#define STAGE_A(b, mh, kt, src)                                             \
    do {                                                                    \
        _Pragma("unroll")                                                   \
        for (int q = 0; q < 2; q++) {                                       \
            int rbase = q * 128 + (mh) * 64 + w * 8;                        \
            async16((src) + (size_t)(rbase + sr) * DIN + (kt) * 64 + sc * 8,\
                    &lds[b][0][rbase * 64]);                                \
        }                                                                   \
    } while (0)

#define STAGE_B(b, nh, kt, src)                                             \
    do {                                                                    \
        _Pragma("unroll")                                                   \
        for (int q = 0; q < 2; q++) {                                       \
            int gi = q * 8 + w;                                             \
            int rbase = (gi >> 2) * 64 + (nh) * 32 + (gi & 3) * 8;          \
            async16((src) + (size_t)(rbase + sr) * DIN + (kt) * 64 + sc * 8,\
                    &lds[b][1][rbase * 64]);                                \
        }                                                                   \
    } while (0)

#define LOAD_A(b, mh)                                                       \
    do {                                                                    \
        _Pragma("unroll")                                                   \
        for (int i = 0; i < 4; i++) {                                       \
            int ra = wm * 128 + (mh) * 64 + i * 16 + l16;                   \
            _Pragma("unroll")                                               \
            for (int kk = 0; kk < 2; kk++) {                                \
                int slot = (kk * 4 + quad) ^ (ra & 7);                      \
                af[i][kk] = *(const bf16x8*)&lds[b][0][ra * 64 + slot * 8]; \
            }                                                               \
        }                                                                   \
    } while (0)

#define LOAD_B(b, nh)                                                       \
    do {                                                                    \
        _Pragma("unroll")                                                   \
        for (int j = 0; j < 2; j++) {                                       \
            int rb = wn * 64 + (nh) * 32 + j * 16 + l16;                    \
            _Pragma("unroll")                                               \
            for (int kk = 0; kk < 2; kk++) {                                \
                int slot = (kk * 4 + quad) ^ (rb & 7);                      \
                bg[nh][j][kk] = *(const bf16x8*)&lds[b][1][rb * 64 + slot * 8]; \
            }                                                               \
        }                                                                   \
    } while (0)

#define MMA(mh, nh)                                                         \
    do {                                                                    \
        __builtin_amdgcn_s_setprio(1);                                      \
        _Pragma("unroll")                                                   \
        for (int i = 0; i < 4; i++)                                         \
            _Pragma("unroll")                                               \
            for (int j = 0; j < 2; j++)                                     \
                _Pragma("unroll")                                           \
                for (int kk = 0; kk < 2; kk++)                              \
                    acc[(mh) * 4 + i][(nh) * 2 + j] =                       \
                        __builtin_amdgcn_mfma_f32_16x16x32_bf16(            \
                            af[i][kk], bg[nh][j][kk],                       \
                            acc[(mh) * 4 + i][(nh) * 2 + j], 0, 0, 0);      \
        __builtin_amdgcn_s_setprio(0);                                      \
    } while (0)

#define BAR()    __builtin_amdgcn_s_barrier()
#define LGKM0()  do { asm volatile("s_waitcnt lgkmcnt(0)" ::: "memory");    \
                      __builtin_amdgcn_sched_barrier(0); } while (0)
#define LGKM8()  asm volatile("s_waitcnt lgkmcnt(8)" ::: "memory")
#define VM6()    asm volatile("s_waitcnt vmcnt(6)" ::: "memory")
#define VM0()    asm volatile("s_waitcnt vmcnt(0)" ::: "memory")
#define VM22()   asm volatile("s_waitcnt vmcnt(22)" ::: "memory")

#define ZERO_ACC()                                                          \
    do { _Pragma("unroll") for (int i = 0; i < 8; i++)                      \
         _Pragma("unroll") for (int j = 0; j < 4; j++)                      \
             acc[i][j] = (f32x4){0.f, 0.f, 0.f, 0.f}; } while (0)

// acc -> LDS as C[256 rows][256 feats] bf16 (128KB). feat XOR'd by quad<<4
// ((row>>2)&3 == quad for writer threads) -> 32 distinct banks, 2 lanes each.
#define EP_DSWRITE()                                                        \
    do { _Pragma("unroll") for (int i = 0; i < 8; i++)                      \
         _Pragma("unroll") for (int j = 0; j < 4; j++)                      \
         _Pragma("unroll") for (int r = 0; r < 4; r++) {                    \
             int row = wm * 128 + i * 16 + quad * 4 + r;                    \
             int ft  = (wn * 64 + j * 16 + l16) ^ (quad << 4);              \
             Cbuf[row * 256 + ft] = f2bf(acc[i][j][r]);                     \
         } } while (0)

#define EP_READ()                                                           \
    do { _Pragma("unroll") for (int ps = 0; ps < 16; ps++) {                \
             int cg = ps * 512 + tid; int row = cg >> 5; int c0 = cg & 31;  \
             int st = row * 256 + ((c0 << 3) ^ (((row >> 2) & 3) << 4));    \
             ctmp[ps] = *(const bf16x8*)&Cbuf[st];                          \
         } } while (0)

#define EP_STORE(PL)                                                        \
    do { _Pragma("unroll") for (int ps = 0; ps < 16; ps++) {                \
             int cg = ps * 512 + tid; int row = cg >> 5; int c0 = cg & 31;  \
             *(bf16x8*)((PL) + (size_t)(M0 + row) * DIN + c0 * 8) = ctmp[ps]; \
         } } while (0)

__global__ __launch_bounds__(512, 2)
void gemm_bf16(const unsigned short* __restrict__ Abf,
               const unsigned short* __restrict__ Bt,
               unsigned short* __restrict__ u_xt,
               unsigned short* __restrict__ u_f,
               unsigned short* __restrict__ u_r) {
    __shared__ __align__(16) unsigned short lds[2][2][256 * 64];  // 128 KiB
    unsigned short* Cbuf = &lds[0][0][0];                         // epilogue alias

    const int tid  = threadIdx.x;
    const int lane = tid & 63;
    const int w    = tid >> 6;          // wave 0..7
    const int wm   = w >> 2, wn = w & 3;
    const int quad = lane >> 4, l16 = lane & 15;

    // Persistent mapping: 256 blocks; xcd gets 8 M-panels x 4 p-groups.
    const int bid = blockIdx.x;
    const int xcd = bid & 7;
    const int k   = bid >> 3;           // 0..31
    const int M0  = (xcd * 8 + (k >> 2)) * 256;
    const int p3  = (k & 3) * 3;        // first of 3 N-tiles

    const unsigned short* Asrc = Abf + (size_t)M0 * DIN;

    f32x4 acc[8][4];
    bf16x8 af[4][2], bg[2][2][2];
    bf16x8 ctmp[16];

    // staging lane coords (8-row groups, 8 chunks/row)
    const int sr = lane >> 3;           // row within group 0..7
    const int sc = (lane & 7) ^ sr;     // source k-chunk (swizzle inverse)

    unsigned short* prev_pl = nullptr;

    #pragma unroll 1
    for (int c = 0; c < 3; c++) {
        const int N0 = (p3 + c) * 256;
        const unsigned short* Bsrc = Bt + (size_t)N0 * DIN;
        const int dir = N0 >= 3 * NOUT;
        const int jj0 = N0 - dir * 3 * NOUT;
        const int plane = jj0 >> 9;
        unsigned short* pl = (plane == 0 ? u_xt : plane == 1 ? u_f : u_r)
                             + dir * NOUT + (jj0 & 511);

        if (c == 0) {
            ZERO_ACC();
            // Prologue: tile0 full -> buf0; tile1 {A0,B1,A1} -> buf1.
            STAGE_A(0, 0, 0, Asrc); STAGE_B(0, 0, 0, Bsrc);
            STAGE_B(0, 1, 0, Bsrc); STAGE_A(0, 1, 0, Asrc);
            STAGE_A(1, 0, 1, Asrc); STAGE_B(1, 1, 1, Bsrc); STAGE_A(1, 1, 1, Asrc);
            VM6();                      // tile0 (8 oldest) landed
            BAR();
        } else {
            // Epilogue of tile c-1 interleaved with prologue of tile c.
            EP_DSWRITE();
            asm volatile("s_waitcnt lgkmcnt(0)" ::: "memory");
            ZERO_ACC();                 // acc dead; ds_writes complete
            BAR();                      // all writes visible
            EP_READ();
            LGKM0();
            BAR();                      // all reads done; LDS free
            STAGE_A(0, 0, 0, Asrc); STAGE_B(0, 0, 0, Bsrc);
            STAGE_B(0, 1, 0, Bsrc); STAGE_A(0, 1, 0, Asrc);
            STAGE_A(1, 0, 1, Asrc); STAGE_B(1, 1, 1, Bsrc); STAGE_A(1, 1, 1, Asrc);
            EP_STORE(prev_pl);          // 16 dwordx4, newer than the stages
            VM22();                     // forces the 8 oldest = tile0; stores drain on
            BAR();
        }

        const int NITER = DIN / 128;    // 8 iterations x 2 K-tiles
        for (int t = 0; t < NITER; t++) {
            const int k1 = 2 * t + 1;
            const bool more = (t < NITER - 1);

            // ---- K-tile 2t from buf0 ----
            // P1: reads A0->af, B0->bg0; stages B0(2t+1)->buf1
            LOAD_A(0, 0); LOAD_B(0, 0);
            STAGE_B(1, 0, k1, Bsrc);
            LGKM8(); BAR(); LGKM0(); MMA(0, 0); BAR();
            // P2: reads B1->bg1; stages A0(2t+2)->buf0
            LOAD_B(0, 1);
            if (more) STAGE_A(0, 0, k1 + 1, Asrc);
            BAR(); LGKM0(); MMA(0, 1); BAR();
            // P3: reads A1->af; stages B1(2t+2)->buf0
            LOAD_A(0, 1);
            if (more) STAGE_B(0, 1, k1 + 1, Bsrc);
            BAR(); LGKM0(); MMA(1, 1); BAR();
            // P4: no reads (af=A1, bg0=B0 held); stages A1(2t+2)->buf0
            if (more) { STAGE_A(0, 1, k1 + 1, Asrc); VM6(); }
            else      { VM0(); }
            BAR(); MMA(1, 0); BAR();

            // ---- K-tile 2t+1 from buf1 ----
            // P5: reads A0->af, B0->bg0; stages B0(2t+2)->buf0
            LOAD_A(1, 0); LOAD_B(1, 0);
            if (more) STAGE_B(0, 0, k1 + 1, Bsrc);
            LGKM8(); BAR(); LGKM0(); MMA(0, 0); BAR();
            // P6: reads B1->bg1; stages A0(2t+3)->buf1
            LOAD_B(1, 1);
            if (more) STAGE_A(1, 0, k1 + 2, Asrc);
            BAR(); LGKM0(); MMA(0, 1); BAR();
            // P7: reads A1->af; stages B1(2t+3)->buf1
            LOAD_A(1, 1);
            if (more) STAGE_B(1, 1, k1 + 2, Bsrc);
            BAR(); LGKM0(); MMA(1, 1); BAR();
            // P8: no reads; stages A1(2t+3)->buf1
            if (more) { STAGE_A(1, 1, k1 + 2, Asrc); VM6(); }
            BAR(); MMA(1, 0); BAR();
        }

        prev_pl = pl;
    }

    // Final epilogue (tile c=2).
    EP_DSWRITE();
    asm volatile("s_waitcnt lgkmcnt(0)" ::: "memory");
    BAR();
    EP_READ();
    LGKM0();
    EP_STORE(prev_pl);
}

// ---------------- chunked SRU scan ----------------
// chain = b*1024 + d*512 + i  (0..16383); element index at time t: t*16384 + chain.
// Segment s: steps j=0..31 at t = t0 + sgn*j; d=0: t0=s*32,sgn=+1; d=1: t0=1023-s*32,sgn=-1.

// Phase A: per (chain, seg) compute A=prod f, B=scan-from-0 result.
__global__ __launch_bounds__(256)
void scan_phaseA(const unsigned short* __restrict__ u_xt, const unsigned short* __restrict__ u_f,
                 const float* __restrict__ bias,
                 float* __restrict__ Aseg, float* __restrict__ Bseg) {
    int g = blockIdx.x * 256 + threadIdx.x;     // s*16384 + chain
    int chain = g & (NCHAIN - 1);
    int s = g >> 14;
    int rest = chain & 1023;                    // d*512 + i
    float bf = bias[rest];

    int d = rest >> 9;
    int t0 = d ? (L_SEQ - 1 - s * SEGLEN) : (s * SEGLEN);
    int sgn = d ? -1 : 1;
    long long idx = (long long)t0 * NCHAIN + chain;
    long long step = (long long)sgn * NCHAIN;

    float c = 0.f, A = 1.f;
    #pragma unroll 8
    for (int j = 0; j < SEGLEN; j++) {
        float xt = bf2f(u_xt[idx]);
        float f = sigmf(bf2f(u_f[idx]) + bf);
        c = f * c + (1.f - f) * xt;
        A *= f;
        idx += step;
    }
    Aseg[g] = A;
    Bseg[g] = c;
}

// Phase B: compose segment carries per chain; write cstart per segment and
// the final c (== hidden state, layout (B,2n) flat == chain).
__global__ __launch_bounds__(256)
void scan_phaseB(const float* __restrict__ Aseg, const float* __restrict__ Bseg,
                 float* __restrict__ cstart, float* __restrict__ c_out) {
    int chain = blockIdx.x * 256 + threadIdx.x;
    float c = 0.f;
    #pragma unroll
    for (int s = 0; s < SEG; s++) {
        int g = s * NCHAIN + chain;
        cstart[g] = c;
        c = Aseg[g] * c + Bseg[g];
    }
    c_out[chain] = c;
}

// Phase C: re-scan each segment from true cstart, emit h (in-place on x) + bf16 copy.
__global__ __launch_bounds__(256)
void scan_phaseC(const unsigned short* __restrict__ u_xt, const unsigned short* __restrict__ u_f,
                 const unsigned short* __restrict__ u_r,
                 float* __restrict__ x, unsigned short* __restrict__ xbf,
                 const float* __restrict__ bias, const float* __restrict__ cstart,
                 int write_bf) {
    int g = blockIdx.x * 256 + threadIdx.x;
    int chain = g & (NCHAIN - 1);
    int s = g >> 14;
    int rest = chain & 1023;
    float bf = bias[rest];
    float br = bias[1024 + rest];

    int d = rest >> 9;
    int t0 = d ? (L_SEQ - 1 - s * SEGLEN) : (s * SEGLEN);
    int sgn = d ? -1 : 1;
    long long idx = (long long)t0 * NCHAIN + chain;
    long long step = (long long)sgn * NCHAIN;

    float c = cstart[g];
    #pragma unroll 4
    for (int j = 0; j < SEGLEN; j++) {
        float xt = bf2f(u_xt[idx]);
        float f = sigmf(bf2f(u_f[idx]) + bf);
        float r = sigmf(bf2f(u_r[idx]) + br);
        float xp = x[idx];
        c = f * c + (1.f - f) * xt;
        float th = 1.f - 2.f / (__expf(2.f * c) + 1.f);
        float h = r * th + (1.f - r) * xp;
        x[idx] = h;
        if (write_bf) xbf[idx] = f2bf(h);
        idx += step;
    }
}

// ---------------- launch ----------------
// d_out: [ x (L*B*1024) | hidden (4*B*1024) ] f32.
// Workspace (158 MB): u_xt 32 | u_f 32 | u_r 32 | xbf 32 | Wt 24 | Aseg 2 | Bseg 2 | cstart 2.
extern "C" void kernel_launch(void* const* d_in, const int* in_sizes, int n_in,
                              void* d_out, int out_size, void* d_ws, size_t ws_size,
                              hipStream_t stream) {
    const int*   tok = (const int*)d_in[0];
    const float* emb = (const float*)d_in[2];
    const float* Ws  = (const float*)d_in[3];
    const float* bs  = (const float*)d_in[4];

    float* out    = (float*)d_out;
    float* x      = out;
    float* hidden = out + (size_t)NTOK * DIN;

    char* ws = (char*)d_ws;
    unsigned short* u_xt   = (unsigned short*)ws;                       // 32 MB
    unsigned short* u_f    = (unsigned short*)(ws + (32u  << 20));      // 32 MB
    unsigned short* u_r    = (unsigned short*)(ws + (64u  << 20));      // 32 MB
    unsigned short* xbf    = (unsigned short*)(ws + (96u  << 20));      // 32 MB
    unsigned short* Wt     = (unsigned short*)(ws + (128u << 20));      // 24 MB
    float*          Aseg   = (float*)(ws + (152u << 20));               // 2 MB
    float*          Bseg   = (float*)(ws + (154u << 20));               // 2 MB
    float*          cstart = (float*)(ws + (156u << 20));               // 2 MB

    transpose_w<<<dim3(NBIG / 32, DIN / 32, NLAYERS), 256, 0, stream>>>(Ws, Wt);
    embed_kernel<<<NTOK, 256, 0, stream>>>(tok, emb, x, xbf);

    const int scan_blocks = NCHAIN * SEG / 256;   // 2048

    for (int l = 0; l < NLAYERS; l++) {
        const unsigned short* Wl = Wt + (size_t)l * NBIG * DIN;
        const float* b = bs + (size_t)l * 4 * NOUT;
        gemm_bf16<<<256, 512, 0, stream>>>(xbf, Wl, u_xt, u_f, u_r);
        scan_phaseA<<<scan_blocks, 256, 0, stream>>>(u_xt, u_f, b, Aseg, Bseg);
        scan_phaseB<<<NCHAIN / 256, 256, 0, stream>>>(Aseg, Bseg, cstart,
                                                      hidden + (size_t)l * BATCH * DIN);
        scan_phaseC<<<scan_blocks, 256, 0, stream>>>(u_xt, u_f, u_r, x, xbf, b, cstart,
                                                     l < NLAYERS - 1);
    }
}

// Round 5
// 913.311 us; speedup vs baseline: 1.3126x; 1.3126x over previous
//
#include <hip/hip_runtime.h>
#include <hip/hip_bf16.h>
#include <cmath>

// Problem constants
#define L_SEQ  1024
#define BATCH  16
#define NOUT   512          // n
#define DIN    1024         // 2n = layer input dim = GEMM K
#define NBIG   3072         // 6n = GEMM N
#define NLAYERS 4
#define NTOK   (L_SEQ * BATCH)   // 16384 = GEMM M
#define NCHAIN 16384             // B * 2 * n independent scan chains
#define SEG    32                // segments per chain
#define SEGLEN (L_SEQ / SEG)     // 32 steps per segment

typedef __attribute__((ext_vector_type(8))) short bf16x8;
typedef __attribute__((ext_vector_type(4))) float f32x4;

__device__ __forceinline__ unsigned short f2bf(float f) {
    unsigned x = __float_as_uint(f);
    unsigned r = (x + 0x7fffu + ((x >> 16) & 1u)) >> 16;   // RNE
    return (unsigned short)r;
}
__device__ __forceinline__ float bf2f(unsigned short hv) {
    return __uint_as_float((unsigned)hv << 16);
}
__device__ __forceinline__ float sigmf(float v) {
    return 1.f / (1.f + __expf(-v));
}
__device__ __forceinline__ void async16(const void* g, const void* l) {
    __builtin_amdgcn_global_load_lds(
        (const __attribute__((address_space(1))) unsigned int*)g,
        (__attribute__((address_space(3))) unsigned int*)l, 16, 0, 0);
}

// ---------------- W convert + transpose: W(1024,3072) f32 -> Wt(3072,1024) bf16 ----------------
__global__ __launch_bounds__(256)
void transpose_w(const float* __restrict__ Ws, unsigned short* __restrict__ Wt) {
    __shared__ float tile[32][33];
    int l = blockIdx.z;
    const float* W = Ws + (size_t)l * DIN * NBIG;
    unsigned short* Wo = Wt + (size_t)l * NBIG * DIN;
    int n0 = blockIdx.x * 32, k0 = blockIdx.y * 32;
    int tx = threadIdx.x & 31, ty = threadIdx.x >> 5;
    #pragma unroll
    for (int i = 0; i < 4; i++)
        tile[ty + 8 * i][tx] = W[(size_t)(k0 + ty + 8 * i) * NBIG + n0 + tx];
    __syncthreads();
    #pragma unroll
    for (int i = 0; i < 4; i++)
        Wo[(size_t)(n0 + ty + 8 * i) * DIN + k0 + tx] = f2bf(tile[tx][ty + 8 * i]);
}

// ---------------- embedding gather: write x fp32 + xbf bf16 ----------------
__global__ void embed_kernel(const int* __restrict__ tok,
                             const float* __restrict__ emb,
                             float* __restrict__ x,
                             unsigned short* __restrict__ xbf) {
    int t = blockIdx.x;
    int row = tok[t];
    float4 v = ((const float4*)(emb + (size_t)row * DIN))[threadIdx.x];
    ((float4*)(x + (size_t)t * DIN))[threadIdx.x] = v;
    ushort4 h;
    h.x = f2bf(v.x); h.y = f2bf(v.y); h.z = f2bf(v.z); h.w = f2bf(v.w);
    ((ushort4*)(xbf + (size_t)t * DIN))[threadIdx.x] = h;
}

// ---------------- bf16 MFMA GEMM: u = x @ W ----------------
// 256x256 tile, BK=64, 8 waves (2M x 4N), per-wave 128x64 output (8x4 frags).
// r3-verified 8-phase schedule + dual-bg register set: bg[0] (B0) loaded at
// P1/P5 is HELD for the P4/P8 MMA(1,0) -> no B0 re-read (saves 4 ds_read_b128
// per wave per K-tile; P4/P8 need no lgkmcnt wait).
//   A-stripe mh = rows {q*128 + mh*64 + w*8}   (what LOAD_A(.,mh) reads)
//   B-stripe nh = rows {g*64  + nh*32 + u*8}   (what LOAD_B(.,nh) reads)
// Reads per K-tile: P1 {A0,B0} -> MMA(0,0); P2 {B1} -> MMA(0,1);
// P3 {A1} -> MMA(1,1); P4 (regs held) -> MMA(1,0).
// Region read at phase p is stage-safe at p+1 (lgkmcnt(0)+barrier per phase).
// Stage slots: P1 B0(2t+1)->buf1 | P2 A0(2t+2) | P3 B1(2t+2) | P4 A1(2t+2)
//            | P5 B0(2t+2)->buf0 | P6 A0(2t+3) | P7 B1(2t+3) | P8 A1(2t+3).
// vmcnt(6) at P4/P8 only: 7 stages (14 loads) outstanding there; oldest 4
// stages == the full next-buffer K-tile. Never drains in steady state.
// LDS chunk-XOR swizzle: 16B chunk c of row r at slot c^(r&7); staged via
// source-side permutation (lane L: dest slot L&7, src chunk (L&7)^(L>>3)).
// Epilogue: planes (xt,f,r) -> bf16, layout [tok][dir*512 + feat].

#define STAGE_A(b, mh, kt, src)                                             \
    do {                                                                    \
        _Pragma("unroll")                                                   \
        for (int q = 0; q < 2; q++) {                                       \
            int rbase = q * 128 + (mh) * 64 + w * 8;                        \
            async16((src) + (size_t)(rbase + sr) * DIN + (kt) * 64 + sc * 8,\
                    &lds[b][0][rbase * 64]);                                \
        }                                                                   \
    } while (0)

#define STAGE_B(b, nh, kt, src)                                             \
    do {                                                                    \
        _Pragma("unroll")                                                   \
        for (int q = 0; q < 2; q++) {                                       \
            int gi = q * 8 + w;                                             \
            int rbase = (gi >> 2) * 64 + (nh) * 32 + (gi & 3) * 8;          \
            async16((src) + (size_t)(rbase + sr) * DIN + (kt) * 64 + sc * 8,\
                    &lds[b][1][rbase * 64]);                                \
        }                                                                   \
    } while (0)

#define LOAD_A(b, mh)                                                       \
    do {                                                                    \
        _Pragma("unroll")                                                   \
        for (int i = 0; i < 4; i++) {                                       \
            int ra = wm * 128 + (mh) * 64 + i * 16 + l16;                   \
            _Pragma("unroll")                                               \
            for (int kk = 0; kk < 2; kk++) {                                \
                int slot = (kk * 4 + quad) ^ (ra & 7);                      \
                af[i][kk] = *(const bf16x8*)&lds[b][0][ra * 64 + slot * 8]; \
            }                                                               \
        }                                                                   \
    } while (0)

#define LOAD_B(b, nh)                                                       \
    do {                                                                    \
        _Pragma("unroll")                                                   \
        for (int j = 0; j < 2; j++) {                                       \
            int rb = wn * 64 + (nh) * 32 + j * 16 + l16;                    \
            _Pragma("unroll")                                               \
            for (int kk = 0; kk < 2; kk++) {                                \
                int slot = (kk * 4 + quad) ^ (rb & 7);                      \
                bg[nh][j][kk] = *(const bf16x8*)&lds[b][1][rb * 64 + slot * 8]; \
            }                                                               \
        }                                                                   \
    } while (0)

#define MMA(mh, nh)                                                         \
    do {                                                                    \
        __builtin_amdgcn_s_setprio(1);                                      \
        _Pragma("unroll")                                                   \
        for (int i = 0; i < 4; i++)                                         \
            _Pragma("unroll")                                               \
            for (int j = 0; j < 2; j++)                                     \
                _Pragma("unroll")                                           \
                for (int kk = 0; kk < 2; kk++)                              \
                    acc[(mh) * 4 + i][(nh) * 2 + j] =                       \
                        __builtin_amdgcn_mfma_f32_16x16x32_bf16(            \
                            af[i][kk], bg[nh][j][kk],                       \
                            acc[(mh) * 4 + i][(nh) * 2 + j], 0, 0, 0);      \
        __builtin_amdgcn_s_setprio(0);                                      \
    } while (0)

#define BAR()   __builtin_amdgcn_s_barrier()
#define LGKM0() do { asm volatile("s_waitcnt lgkmcnt(0)" ::: "memory");     \
                     __builtin_amdgcn_sched_barrier(0); } while (0)
#define LGKM8() asm volatile("s_waitcnt lgkmcnt(8)" ::: "memory")
#define VM6()   asm volatile("s_waitcnt vmcnt(6)" ::: "memory")
#define VM0()   asm volatile("s_waitcnt vmcnt(0)" ::: "memory")

__global__ __launch_bounds__(512)
void gemm_bf16(const unsigned short* __restrict__ Abf,
               const unsigned short* __restrict__ Bt,
               unsigned short* __restrict__ u_xt,
               unsigned short* __restrict__ u_f,
               unsigned short* __restrict__ u_r) {
    __shared__ __align__(16) unsigned short lds[2][2][256 * 64];  // [buf][A/B]

    const int tid  = threadIdx.x;
    const int lane = tid & 63;
    const int w    = tid >> 6;          // wave 0..7
    const int wm   = w >> 2, wn = w & 3;
    const int quad = lane >> 4, l16 = lane & 15;

    // XCD-aware bijective swizzle: grid 12x64 = 768 blocks, 768 % 8 == 0.
    const int flat = blockIdx.y * (NBIG / 256) + blockIdx.x;
    const int swz  = (flat & 7) * (NTOK / 256 * NBIG / 256 / 8) + (flat >> 3);
    const int M0 = (swz / (NBIG / 256)) * 256;
    const int N0 = (swz % (NBIG / 256)) * 256;

    const unsigned short* Asrc = Abf + (size_t)M0 * DIN;
    const unsigned short* Bsrc = Bt  + (size_t)N0 * DIN;

    f32x4 acc[8][4];
    #pragma unroll
    for (int i = 0; i < 8; i++)
        #pragma unroll
        for (int j = 0; j < 4; j++)
            acc[i][j] = (f32x4){0.f, 0.f, 0.f, 0.f};

    // staging lane coords (8-row groups, 8 chunks/row)
    const int sr = lane >> 3;           // row within group 0..7
    const int sc = (lane & 7) ^ sr;     // source k-chunk (swizzle inverse)

    bf16x8 af[4][2], bg[2][2][2];

    // Prologue: tile0 (all 4 stripes) -> buf0; tile1 {A0,B1,A1} -> buf1.
    // vmcnt(6) leaves exactly tile1's 3 stripes in flight; tile0 landed.
    STAGE_A(0, 0, 0, Asrc); STAGE_B(0, 0, 0, Bsrc);
    STAGE_B(0, 1, 0, Bsrc); STAGE_A(0, 1, 0, Asrc);
    STAGE_A(1, 0, 1, Asrc); STAGE_B(1, 1, 1, Bsrc); STAGE_A(1, 1, 1, Asrc);
    VM6();
    BAR();

    const int NITER = DIN / 128;        // 8 iterations x 2 K-tiles
    for (int t = 0; t < NITER; t++) {
        const int k1 = 2 * t + 1;
        const bool more = (t < NITER - 1);

        // ---- K-tile 2t from buf0 ----
        // P1: reads A0->af, B0->bg[0]; stages B0(2t+1)->buf1
        LOAD_A(0, 0); LOAD_B(0, 0);
        STAGE_B(1, 0, k1, Bsrc);
        LGKM8(); BAR(); LGKM0(); MMA(0, 0); BAR();
        // P2: reads B1->bg[1]; stages A0(2t+2)->buf0 (A0 read at P1)
        LOAD_B(0, 1);
        if (more) STAGE_A(0, 0, k1 + 1, Asrc);
        BAR(); LGKM0(); MMA(0, 1); BAR();
        // P3: reads A1->af; stages B1(2t+2)->buf0 (B1 read at P2)
        LOAD_A(0, 1);
        if (more) STAGE_B(0, 1, k1 + 1, Bsrc);
        BAR(); LGKM0(); MMA(1, 1); BAR();
        // P4: no ds_read (af=A1, bg[0]=B0 held); stages A1(2t+2)->buf0;
        //     vmcnt(6): oldest 4 of 7 outstanding stages == full tile 2t+1
        if (more) { STAGE_A(0, 1, k1 + 1, Asrc); VM6(); }
        else      { VM0(); }
        BAR(); MMA(1, 0); BAR();

        // ---- K-tile 2t+1 from buf1 ----
        // P5: reads A0->af, B0->bg[0]; stages B0(2t+2)->buf0 (B0 read at P1)
        LOAD_A(1, 0); LOAD_B(1, 0);
        if (more) STAGE_B(0, 0, k1 + 1, Bsrc);
        LGKM8(); BAR(); LGKM0(); MMA(0, 0); BAR();
        // P6: reads B1->bg[1]; stages A0(2t+3)->buf1 (A0 read at P5)
        LOAD_B(1, 1);
        if (more) STAGE_A(1, 0, k1 + 2, Asrc);
        BAR(); LGKM0(); MMA(0, 1); BAR();
        // P7: reads A1->af; stages B1(2t+3)->buf1 (B1 read at P6)
        LOAD_A(1, 1);
        if (more) STAGE_B(1, 1, k1 + 2, Bsrc);
        BAR(); LGKM0(); MMA(1, 1); BAR();
        // P8: no ds_read; stages A1(2t+3)->buf1 (A1 read at P7);
        //     vmcnt(6): oldest 4 outstanding == full tile 2t+2
        if (more) { STAGE_A(1, 1, k1 + 2, Asrc); VM6(); }
        BAR(); MMA(1, 0); BAR();
    }

    // Epilogue: split planes, bf16 store.
    #pragma unroll
    for (int i = 0; i < 8; i++) {
        int gm = M0 + wm * 128 + i * 16 + quad * 4;
        #pragma unroll
        for (int j = 0; j < 4; j++) {
            int gn = N0 + wn * 64 + j * 16 + l16;
            int dir  = gn >= 3 * NOUT;
            int jj   = gn - dir * 3 * NOUT;
            int plane = jj >> 9;          // 0:xt 1:f 2:r (uniform per 16-tile)
            int feat  = jj & 511;
            unsigned short* p = (plane == 0 ? u_xt : plane == 1 ? u_f : u_r)
                                + (size_t)gm * DIN + dir * NOUT + feat;
            #pragma unroll
            for (int r = 0; r < 4; r++) p[(size_t)r * DIN] = f2bf(acc[i][j][r]);
        }
    }
}

// ---------------- chunked SRU scan ----------------
// chain = b*1024 + d*512 + i  (0..16383); element index at time t: t*16384 + chain.
// Segment s: steps j=0..31 at t = t0 + sgn*j; d=0: t0=s*32,sgn=+1; d=1: t0=1023-s*32,sgn=-1.
// Vectorized 2 chains/thread (chains 2i,2i+1: same b, same d; idx stays 4/8B
// aligned) -> uint loads of bf16 pairs, float2 for fp32. Halves wave count.

// Phase A: per (chain-pair, seg) compute A=prod f, B=scan-from-0 result.
__global__ __launch_bounds__(256)
void scan_phaseA(const unsigned short* __restrict__ u_xt, const unsigned short* __restrict__ u_f,
                 const float* __restrict__ bias,
                 float* __restrict__ Aseg, float* __restrict__ Bseg) {
    int hgl = blockIdx.x * 256 + threadIdx.x;   // s*8192 + chain/2
    int c2 = hgl & (NCHAIN / 2 - 1);
    int s = hgl >> 13;
    int chain = c2 * 2;
    int rest = chain & 1023;                    // d*512 + i  (even)
    float bf0 = bias[rest], bf1 = bias[rest + 1];

    int d = rest >> 9;
    int t0 = d ? (L_SEQ - 1 - s * SEGLEN) : (s * SEGLEN);
    int sgn = d ? -1 : 1;
    long long idx = (long long)t0 * NCHAIN + chain;
    long long step = (long long)sgn * NCHAIN;

    float c0 = 0.f, A0 = 1.f, c1 = 0.f, A1 = 1.f;
    #pragma unroll 8
    for (int j = 0; j < SEGLEN; j++) {
        unsigned xt2 = *(const unsigned*)(u_xt + idx);
        unsigned f2v = *(const unsigned*)(u_f + idx);
        float xt0 = bf2f((unsigned short)xt2), xt1 = bf2f((unsigned short)(xt2 >> 16));
        float f0 = sigmf(bf2f((unsigned short)f2v) + bf0);
        float f1 = sigmf(bf2f((unsigned short)(f2v >> 16)) + bf1);
        c0 = f0 * c0 + (1.f - f0) * xt0;  A0 *= f0;
        c1 = f1 * c1 + (1.f - f1) * xt1;  A1 *= f1;
        idx += step;
    }
    int g = s * NCHAIN + chain;
    *(float2*)(Aseg + g) = make_float2(A0, A1);
    *(float2*)(Bseg + g) = make_float2(c0, c1);
}

// Phase B: compose segment carries per chain; write cstart per segment and
// the final c (== hidden state, layout (B,2n) flat == chain).
__global__ __launch_bounds__(256)
void scan_phaseB(const float* __restrict__ Aseg, const float* __restrict__ Bseg,
                 float* __restrict__ cstart, float* __restrict__ c_out) {
    int chain = blockIdx.x * 256 + threadIdx.x;
    float c = 0.f;
    #pragma unroll
    for (int s = 0; s < SEG; s++) {
        int g = s * NCHAIN + chain;
        cstart[g] = c;
        c = Aseg[g] * c + Bseg[g];
    }
    c_out[chain] = c;
}

// Phase C: re-scan each segment from true cstart, emit h (in-place on x) + bf16 copy.
__global__ __launch_bounds__(256)
void scan_phaseC(const unsigned short* __restrict__ u_xt, const unsigned short* __restrict__ u_f,
                 const unsigned short* __restrict__ u_r,
                 float* __restrict__ x, unsigned short* __restrict__ xbf,
                 const float* __restrict__ bias, const float* __restrict__ cstart,
                 int write_bf) {
    int hgl = blockIdx.x * 256 + threadIdx.x;   // s*8192 + chain/2
    int c2 = hgl & (NCHAIN / 2 - 1);
    int s = hgl >> 13;
    int chain = c2 * 2;
    int rest = chain & 1023;
    float bf0 = bias[rest],        bf1 = bias[rest + 1];
    float br0 = bias[1024 + rest], br1 = bias[1024 + rest + 1];

    int d = rest >> 9;
    int t0 = d ? (L_SEQ - 1 - s * SEGLEN) : (s * SEGLEN);
    int sgn = d ? -1 : 1;
    long long idx = (long long)t0 * NCHAIN + chain;
    long long step = (long long)sgn * NCHAIN;

    float2 cs = *(const float2*)(cstart + (size_t)s * NCHAIN + chain);
    float c0 = cs.x, c1 = cs.y;
    #pragma unroll 4
    for (int j = 0; j < SEGLEN; j++) {
        unsigned xt2 = *(const unsigned*)(u_xt + idx);
        unsigned f2v = *(const unsigned*)(u_f + idx);
        unsigned r2v = *(const unsigned*)(u_r + idx);
        float2 xp = *(const float2*)(x + idx);
        float f0 = sigmf(bf2f((unsigned short)f2v) + bf0);
        float f1 = sigmf(bf2f((unsigned short)(f2v >> 16)) + bf1);
        float r0 = sigmf(bf2f((unsigned short)r2v) + br0);
        float r1 = sigmf(bf2f((unsigned short)(r2v >> 16)) + br1);
        c0 = f0 * c0 + (1.f - f0) * bf2f((unsigned short)xt2);
        c1 = f1 * c1 + (1.f - f1) * bf2f((unsigned short)(xt2 >> 16));
        float th0 = 1.f - 2.f / (__expf(2.f * c0) + 1.f);
        float th1 = 1.f - 2.f / (__expf(2.f * c1) + 1.f);
        float h0 = r0 * th0 + (1.f - r0) * xp.x;
        float h1 = r1 * th1 + (1.f - r1) * xp.y;
        *(float2*)(x + idx) = make_float2(h0, h1);
        if (write_bf)
            *(unsigned*)(xbf + idx) = (unsigned)f2bf(h0) | ((unsigned)f2bf(h1) << 16);
        idx += step;
    }
}

// ---------------- launch ----------------
// d_out: [ x (L*B*1024) | hidden (4*B*1024) ] f32.
// Workspace (158 MB): u_xt 32 | u_f 32 | u_r 32 | xbf 32 | Wt 24 | Aseg 2 | Bseg 2 | cstart 2.
extern "C" void kernel_launch(void* const* d_in, const int* in_sizes, int n_in,
                              void* d_out, int out_size, void* d_ws, size_t ws_size,
                              hipStream_t stream) {
    const int*   tok = (const int*)d_in[0];
    const float* emb = (const float*)d_in[2];
    const float* Ws  = (const float*)d_in[3];
    const float* bs  = (const float*)d_in[4];

    float* out    = (float*)d_out;
    float* x      = out;
    float* hidden = out + (size_t)NTOK * DIN;

    char* ws = (char*)d_ws;
    unsigned short* u_xt   = (unsigned short*)ws;                       // 32 MB
    unsigned short* u_f    = (unsigned short*)(ws + (32u  << 20));      // 32 MB
    unsigned short* u_r    = (unsigned short*)(ws + (64u  << 20));      // 32 MB
    unsigned short* xbf    = (unsigned short*)(ws + (96u  << 20));      // 32 MB
    unsigned short* Wt     = (unsigned short*)(ws + (128u << 20));      // 24 MB
    float*          Aseg   = (float*)(ws + (152u << 20));               // 2 MB
    float*          Bseg   = (float*)(ws + (154u << 20));               // 2 MB
    float*          cstart = (float*)(ws + (156u << 20));               // 2 MB

    transpose_w<<<dim3(NBIG / 32, DIN / 32, NLAYERS), 256, 0, stream>>>(Ws, Wt);
    embed_kernel<<<NTOK, 256, 0, stream>>>(tok, emb, x, xbf);

    const int scan_blocks2 = NCHAIN * SEG / 2 / 256;   // 1024 (2 chains/thread)

    for (int l = 0; l < NLAYERS; l++) {
        const unsigned short* Wl = Wt + (size_t)l * NBIG * DIN;
        const float* b = bs + (size_t)l * 4 * NOUT;
        gemm_bf16<<<dim3(NBIG / 256, NTOK / 256), 512, 0, stream>>>(xbf, Wl, u_xt, u_f, u_r);
        scan_phaseA<<<scan_blocks2, 256, 0, stream>>>(u_xt, u_f, b, Aseg, Bseg);
        scan_phaseB<<<NCHAIN / 256, 256, 0, stream>>>(Aseg, Bseg, cstart,
                                                      hidden + (size_t)l * BATCH * DIN);
        scan_phaseC<<<scan_blocks2, 256, 0, stream>>>(u_xt, u_f, u_r, x, xbf, b, cstart,
                                                      l < NLAYERS - 1);
    }
}

// Round 6
// 907.746 us; speedup vs baseline: 1.3206x; 1.0061x over previous
//
#include <hip/hip_runtime.h>
#include <hip/hip_bf16.h>
#include <cmath>

// Problem constants
#define L_SEQ  1024
#define BATCH  16
#define NOUT   512          // n
#define DIN    1024         // 2n = layer input dim = GEMM K
#define NBIG   3072         // 6n = GEMM N
#define NLAYERS 4
#define NTOK   (L_SEQ * BATCH)   // 16384 = GEMM M
#define NCHAIN 16384             // B * 2 * n independent scan chains
#define SEG    32                // segments per chain
#define SEGLEN (L_SEQ / SEG)     // 32 steps per segment

typedef __attribute__((ext_vector_type(8))) short bf16x8;
typedef __attribute__((ext_vector_type(4))) float f32x4;

__device__ __forceinline__ unsigned short f2bf(float f) {
    unsigned x = __float_as_uint(f);
    unsigned r = (x + 0x7fffu + ((x >> 16) & 1u)) >> 16;   // RNE
    return (unsigned short)r;
}
__device__ __forceinline__ float bf2f(unsigned short hv) {
    return __uint_as_float((unsigned)hv << 16);
}
__device__ __forceinline__ float sigmf(float v) {
    return 1.f / (1.f + __expf(-v));
}
__device__ __forceinline__ void async16(const void* g, const void* l) {
    __builtin_amdgcn_global_load_lds(
        (const __attribute__((address_space(1))) unsigned int*)g,
        (__attribute__((address_space(3))) unsigned int*)l, 16, 0, 0);
}

// ---------------- W convert + transpose: W(1024,3072) f32 -> Wt(3072,1024) bf16 ----------------
__global__ __launch_bounds__(256)
void transpose_w(const float* __restrict__ Ws, unsigned short* __restrict__ Wt) {
    __shared__ float tile[32][33];
    int l = blockIdx.z;
    const float* W = Ws + (size_t)l * DIN * NBIG;
    unsigned short* Wo = Wt + (size_t)l * NBIG * DIN;
    int n0 = blockIdx.x * 32, k0 = blockIdx.y * 32;
    int tx = threadIdx.x & 31, ty = threadIdx.x >> 5;
    #pragma unroll
    for (int i = 0; i < 4; i++)
        tile[ty + 8 * i][tx] = W[(size_t)(k0 + ty + 8 * i) * NBIG + n0 + tx];
    __syncthreads();
    #pragma unroll
    for (int i = 0; i < 4; i++)
        Wo[(size_t)(n0 + ty + 8 * i) * DIN + k0 + tx] = f2bf(tile[tx][ty + 8 * i]);
}

// ---------------- embedding gather: write x fp32 + xbf bf16 ----------------
__global__ void embed_kernel(const int* __restrict__ tok,
                             const float* __restrict__ emb,
                             float* __restrict__ x,
                             unsigned short* __restrict__ xbf) {
    int t = blockIdx.x;
    int row = tok[t];
    float4 v = ((const float4*)(emb + (size_t)row * DIN))[threadIdx.x];
    ((float4*)(x + (size_t)t * DIN))[threadIdx.x] = v;
    ushort4 h;
    h.x = f2bf(v.x); h.y = f2bf(v.y); h.z = f2bf(v.z); h.w = f2bf(v.w);
    ((ushort4*)(xbf + (size_t)t * DIN))[threadIdx.x] = h;
}

// ---------------- bf16 MFMA GEMM: u = x @ W ----------------
// 256x256 tile, BK=64, 8 waves (2M x 4N), per-wave 128x64 output (8x4 frags).
// r3/r5-verified 8-phase schedule + dual-bg (B0 held in regs for P4/P8).
// NEW (r6): vectorized epilogue — after the K-loop the 128KB LDS is dead, so
// acc -> ds_write Cbuf[256][256] bf16 (feat ^ (quad<<4) swizzle, 2-way=free,
// r4-verified) -> bar -> 16x ds_read_b128 -> 16x coalesced dwordx4 stores
// (1KB/instr, full lines). Replaces 128 scattered 2B stores per thread.
// Schedule notes (unchanged, verified):
// Stage slots: P1 B0(2t+1)->buf1 | P2 A0(2t+2) | P3 B1(2t+2) | P4 A1(2t+2)
//            | P5 B0(2t+2)->buf0 | P6 A0(2t+3) | P7 B1(2t+3) | P8 A1(2t+3).
// vmcnt(6) at P4/P8 only; region read at phase p is stage-safe at p+1.
// LDS chunk-XOR swizzle: chunk c of row r at slot c^(r&7); staged via
// source-side permutation (lane L: dest slot L&7, src chunk (L&7)^(L>>3)).

#define STAGE_A(b, mh, kt, src)                                             \
    do {                                                                    \
        _Pragma("unroll")                                                   \
        for (int q = 0; q < 2; q++) {                                       \
            int rbase = q * 128 + (mh) * 64 + w * 8;                        \
            async16((src) + (size_t)(rbase + sr) * DIN + (kt) * 64 + sc * 8,\
                    &lds[b][0][rbase * 64]);                                \
        }                                                                   \
    } while (0)

#define STAGE_B(b, nh, kt, src)                                             \
    do {                                                                    \
        _Pragma("unroll")                                                   \
        for (int q = 0; q < 2; q++) {                                       \
            int gi = q * 8 + w;                                             \
            int rbase = (gi >> 2) * 64 + (nh) * 32 + (gi & 3) * 8;          \
            async16((src) + (size_t)(rbase + sr) * DIN + (kt) * 64 + sc * 8,\
                    &lds[b][1][rbase * 64]);                                \
        }                                                                   \
    } while (0)

#define LOAD_A(b, mh)                                                       \
    do {                                                                    \
        _Pragma("unroll")                                                   \
        for (int i = 0; i < 4; i++) {                                       \
            int ra = wm * 128 + (mh) * 64 + i * 16 + l16;                   \
            _Pragma("unroll")                                               \
            for (int kk = 0; kk < 2; kk++) {                                \
                int slot = (kk * 4 + quad) ^ (ra & 7);                      \
                af[i][kk] = *(const bf16x8*)&lds[b][0][ra * 64 + slot * 8]; \
            }                                                               \
        }                                                                   \
    } while (0)

#define LOAD_B(b, nh)                                                       \
    do {                                                                    \
        _Pragma("unroll")                                                   \
        for (int j = 0; j < 2; j++) {                                       \
            int rb = wn * 64 + (nh) * 32 + j * 16 + l16;                    \
            _Pragma("unroll")                                               \
            for (int kk = 0; kk < 2; kk++) {                                \
                int slot = (kk * 4 + quad) ^ (rb & 7);                      \
                bg[nh][j][kk] = *(const bf16x8*)&lds[b][1][rb * 64 + slot * 8]; \
            }                                                               \
        }                                                                   \
    } while (0)

#define MMA(mh, nh)                                                         \
    do {                                                                    \
        __builtin_amdgcn_s_setprio(1);                                      \
        _Pragma("unroll")                                                   \
        for (int i = 0; i < 4; i++)                                         \
            _Pragma("unroll")                                               \
            for (int j = 0; j < 2; j++)                                     \
                _Pragma("unroll")                                           \
                for (int kk = 0; kk < 2; kk++)                              \
                    acc[(mh) * 4 + i][(nh) * 2 + j] =                       \
                        __builtin_amdgcn_mfma_f32_16x16x32_bf16(            \
                            af[i][kk], bg[nh][j][kk],                       \
                            acc[(mh) * 4 + i][(nh) * 2 + j], 0, 0, 0);      \
        __builtin_amdgcn_s_setprio(0);                                      \
    } while (0)

#define BAR()   __builtin_amdgcn_s_barrier()
#define LGKM0() do { asm volatile("s_waitcnt lgkmcnt(0)" ::: "memory");     \
                     __builtin_amdgcn_sched_barrier(0); } while (0)
#define LGKM8() asm volatile("s_waitcnt lgkmcnt(8)" ::: "memory")
#define VM6()   asm volatile("s_waitcnt vmcnt(6)" ::: "memory")
#define VM0()   asm volatile("s_waitcnt vmcnt(0)" ::: "memory")

__global__ __launch_bounds__(512)
void gemm_bf16(const unsigned short* __restrict__ Abf,
               const unsigned short* __restrict__ Bt,
               unsigned short* __restrict__ u_xt,
               unsigned short* __restrict__ u_f,
               unsigned short* __restrict__ u_r) {
    __shared__ __align__(16) unsigned short lds[2][2][256 * 64];  // 128 KiB
    unsigned short* Cbuf = &lds[0][0][0];                         // epilogue alias

    const int tid  = threadIdx.x;
    const int lane = tid & 63;
    const int w    = tid >> 6;          // wave 0..7
    const int wm   = w >> 2, wn = w & 3;
    const int quad = lane >> 4, l16 = lane & 15;

    // XCD-aware bijective swizzle: grid 12x64 = 768 blocks, 768 % 8 == 0.
    const int flat = blockIdx.y * (NBIG / 256) + blockIdx.x;
    const int swz  = (flat & 7) * (NTOK / 256 * NBIG / 256 / 8) + (flat >> 3);
    const int M0 = (swz / (NBIG / 256)) * 256;
    const int N0 = (swz % (NBIG / 256)) * 256;

    const unsigned short* Asrc = Abf + (size_t)M0 * DIN;
    const unsigned short* Bsrc = Bt  + (size_t)N0 * DIN;

    // Output plane: each 256-wide N-tile lies in exactly one plane+dir.
    const int dir   = N0 >= 3 * NOUT;
    const int jj0   = N0 - dir * 3 * NOUT;
    const int plane = jj0 >> 9;
    unsigned short* pl = (plane == 0 ? u_xt : plane == 1 ? u_f : u_r)
                         + dir * NOUT + (jj0 & 511);

    f32x4 acc[8][4];
    #pragma unroll
    for (int i = 0; i < 8; i++)
        #pragma unroll
        for (int j = 0; j < 4; j++)
            acc[i][j] = (f32x4){0.f, 0.f, 0.f, 0.f};

    // staging lane coords (8-row groups, 8 chunks/row)
    const int sr = lane >> 3;           // row within group 0..7
    const int sc = (lane & 7) ^ sr;     // source k-chunk (swizzle inverse)

    bf16x8 af[4][2], bg[2][2][2];

    // Prologue: tile0 (all 4 stripes) -> buf0; tile1 {A0,B1,A1} -> buf1.
    STAGE_A(0, 0, 0, Asrc); STAGE_B(0, 0, 0, Bsrc);
    STAGE_B(0, 1, 0, Bsrc); STAGE_A(0, 1, 0, Asrc);
    STAGE_A(1, 0, 1, Asrc); STAGE_B(1, 1, 1, Bsrc); STAGE_A(1, 1, 1, Asrc);
    VM6();
    BAR();

    const int NITER = DIN / 128;        // 8 iterations x 2 K-tiles
    for (int t = 0; t < NITER; t++) {
        const int k1 = 2 * t + 1;
        const bool more = (t < NITER - 1);

        // ---- K-tile 2t from buf0 ----
        LOAD_A(0, 0); LOAD_B(0, 0);
        STAGE_B(1, 0, k1, Bsrc);
        LGKM8(); BAR(); LGKM0(); MMA(0, 0); BAR();
        LOAD_B(0, 1);
        if (more) STAGE_A(0, 0, k1 + 1, Asrc);
        BAR(); LGKM0(); MMA(0, 1); BAR();
        LOAD_A(0, 1);
        if (more) STAGE_B(0, 1, k1 + 1, Bsrc);
        BAR(); LGKM0(); MMA(1, 1); BAR();
        if (more) { STAGE_A(0, 1, k1 + 1, Asrc); VM6(); }
        else      { VM0(); }
        BAR(); MMA(1, 0); BAR();

        // ---- K-tile 2t+1 from buf1 ----
        LOAD_A(1, 0); LOAD_B(1, 0);
        if (more) STAGE_B(0, 0, k1 + 1, Bsrc);
        LGKM8(); BAR(); LGKM0(); MMA(0, 0); BAR();
        LOAD_B(1, 1);
        if (more) STAGE_A(1, 0, k1 + 2, Asrc);
        BAR(); LGKM0(); MMA(0, 1); BAR();
        LOAD_A(1, 1);
        if (more) STAGE_B(1, 1, k1 + 2, Bsrc);
        BAR(); LGKM0(); MMA(1, 1); BAR();
        if (more) { STAGE_A(1, 1, k1 + 2, Asrc); VM6(); }
        BAR(); MMA(1, 0); BAR();
    }

    // ---- Vectorized epilogue (LDS transpose; all loads drained by VM0) ----
    // Write: logical feat F of row stored at physical ft = F ^ (quad<<4),
    // quad = (row>>2)&3 for the writer -> 2-way bank alias (free).
    #pragma unroll
    for (int i = 0; i < 8; i++)
        #pragma unroll
        for (int j = 0; j < 4; j++)
            #pragma unroll
            for (int r = 0; r < 4; r++) {
                int row = wm * 128 + i * 16 + quad * 4 + r;
                int ft  = (wn * 64 + j * 16 + l16) ^ (quad << 4);
                Cbuf[row * 256 + ft] = f2bf(acc[i][j][r]);
            }
    asm volatile("s_waitcnt lgkmcnt(0)" ::: "memory");
    BAR();
    // Read physical ((c0*8) ^ XOR) -> logical feats c0*8..c0*8+7; store 16B.
    bf16x8 ctmp[16];
    #pragma unroll
    for (int ps = 0; ps < 16; ps++) {
        int cg = ps * 512 + tid; int row = cg >> 5; int c0 = cg & 31;
        int st = row * 256 + ((c0 << 3) ^ (((row >> 2) & 3) << 4));
        ctmp[ps] = *(const bf16x8*)&Cbuf[st];
    }
    LGKM0();
    #pragma unroll
    for (int ps = 0; ps < 16; ps++) {
        int cg = ps * 512 + tid; int row = cg >> 5; int c0 = cg & 31;
        *(bf16x8*)(pl + (size_t)(M0 + row) * DIN + c0 * 8) = ctmp[ps];
    }
}

// ---------------- chunked SRU scan ----------------
// chain = b*1024 + d*512 + i  (0..16383); element index at time t: t*16384 + chain.
// Segment s: steps j=0..31 at t = t0 + sgn*j; d=0: t0=s*32,sgn=+1; d=1: t0=1023-s*32,sgn=-1.
// Vectorized 4 chains/thread (chains 4i..4i+3: same b, same d; 512 is a
// multiple of 4 so the d-boundary is never crossed) -> uint2 loads of bf16
// quads, float4 for fp32.

// Phase A: per (chain-quad, seg) compute A=prod f, B=scan-from-0 result.
__global__ __launch_bounds__(256)
void scan_phaseA(const unsigned short* __restrict__ u_xt, const unsigned short* __restrict__ u_f,
                 const float* __restrict__ bias,
                 float* __restrict__ Aseg, float* __restrict__ Bseg) {
    int hgl = blockIdx.x * 256 + threadIdx.x;   // s*4096 + chain/4
    int c4 = hgl & (NCHAIN / 4 - 1);
    int s = hgl >> 12;
    int chain = c4 * 4;
    int rest = chain & 1023;                    // d*512 + i  (multiple of 4)
    float bf[4];
    #pragma unroll
    for (int v = 0; v < 4; v++) bf[v] = bias[rest + v];

    int d = rest >> 9;
    int t0 = d ? (L_SEQ - 1 - s * SEGLEN) : (s * SEGLEN);
    int sgn = d ? -1 : 1;
    long long idx = (long long)t0 * NCHAIN + chain;
    long long step = (long long)sgn * NCHAIN;

    float c[4] = {0.f, 0.f, 0.f, 0.f}, A[4] = {1.f, 1.f, 1.f, 1.f};
    #pragma unroll 4
    for (int j = 0; j < SEGLEN; j++) {
        uint2 xt4 = *(const uint2*)(u_xt + idx);
        uint2 f4  = *(const uint2*)(u_f + idx);
        #pragma unroll
        for (int v = 0; v < 4; v++) {
            unsigned xw = (v < 2) ? xt4.x : xt4.y;
            unsigned fw = (v < 2) ? f4.x : f4.y;
            float xt = bf2f((unsigned short)(xw >> ((v & 1) * 16)));
            float f  = sigmf(bf2f((unsigned short)(fw >> ((v & 1) * 16))) + bf[v]);
            c[v] = f * c[v] + (1.f - f) * xt;
            A[v] *= f;
        }
        idx += step;
    }
    int g = s * NCHAIN + chain;
    *(float4*)(Aseg + g) = make_float4(A[0], A[1], A[2], A[3]);
    *(float4*)(Bseg + g) = make_float4(c[0], c[1], c[2], c[3]);
}

// Phase B: compose segment carries per chain (2 chains/thread); write cstart
// per segment and the final c (== hidden state, layout (B,2n) flat == chain).
__global__ __launch_bounds__(256)
void scan_phaseB(const float* __restrict__ Aseg, const float* __restrict__ Bseg,
                 float* __restrict__ cstart, float* __restrict__ c_out) {
    int c2 = (blockIdx.x * 256 + threadIdx.x) * 2;
    float cx = 0.f, cy = 0.f;
    #pragma unroll
    for (int s = 0; s < SEG; s++) {
        int g = s * NCHAIN + c2;
        float2 A = *(const float2*)(Aseg + g);
        float2 B = *(const float2*)(Bseg + g);
        *(float2*)(cstart + g) = make_float2(cx, cy);
        cx = A.x * cx + B.x;
        cy = A.y * cy + B.y;
    }
    *(float2*)(c_out + c2) = make_float2(cx, cy);
}

// Phase C: re-scan each segment from true cstart, emit h (in-place on x) + bf16 copy.
__global__ __launch_bounds__(256)
void scan_phaseC(const unsigned short* __restrict__ u_xt, const unsigned short* __restrict__ u_f,
                 const unsigned short* __restrict__ u_r,
                 float* __restrict__ x, unsigned short* __restrict__ xbf,
                 const float* __restrict__ bias, const float* __restrict__ cstart,
                 int write_bf) {
    int hgl = blockIdx.x * 256 + threadIdx.x;   // s*4096 + chain/4
    int c4 = hgl & (NCHAIN / 4 - 1);
    int s = hgl >> 12;
    int chain = c4 * 4;
    int rest = chain & 1023;
    float bf[4], br[4];
    #pragma unroll
    for (int v = 0; v < 4; v++) { bf[v] = bias[rest + v]; br[v] = bias[1024 + rest + v]; }

    int d = rest >> 9;
    int t0 = d ? (L_SEQ - 1 - s * SEGLEN) : (s * SEGLEN);
    int sgn = d ? -1 : 1;
    long long idx = (long long)t0 * NCHAIN + chain;
    long long step = (long long)sgn * NCHAIN;

    float4 cs = *(const float4*)(cstart + (size_t)s * NCHAIN + chain);
    float c[4] = {cs.x, cs.y, cs.z, cs.w};
    #pragma unroll 2
    for (int j = 0; j < SEGLEN; j++) {
        uint2 xt4 = *(const uint2*)(u_xt + idx);
        uint2 f4  = *(const uint2*)(u_f + idx);
        uint2 r4  = *(const uint2*)(u_r + idx);
        float4 xp = *(const float4*)(x + idx);
        float h[4];
        #pragma unroll
        for (int v = 0; v < 4; v++) {
            unsigned xw = (v < 2) ? xt4.x : xt4.y;
            unsigned fw = (v < 2) ? f4.x : f4.y;
            unsigned rw = (v < 2) ? r4.x : r4.y;
            float xpv = (v == 0) ? xp.x : (v == 1) ? xp.y : (v == 2) ? xp.z : xp.w;
            float f = sigmf(bf2f((unsigned short)(fw >> ((v & 1) * 16))) + bf[v]);
            float r = sigmf(bf2f((unsigned short)(rw >> ((v & 1) * 16))) + br[v]);
            c[v] = f * c[v] + (1.f - f) * bf2f((unsigned short)(xw >> ((v & 1) * 16)));
            float th = 1.f - 2.f / (__expf(2.f * c[v]) + 1.f);
            h[v] = r * th + (1.f - r) * xpv;
        }
        *(float4*)(x + idx) = make_float4(h[0], h[1], h[2], h[3]);
        if (write_bf) {
            uint2 hb;
            hb.x = (unsigned)f2bf(h[0]) | ((unsigned)f2bf(h[1]) << 16);
            hb.y = (unsigned)f2bf(h[2]) | ((unsigned)f2bf(h[3]) << 16);
            *(uint2*)(xbf + idx) = hb;
        }
        idx += step;
    }
}

// ---------------- launch ----------------
// d_out: [ x (L*B*1024) | hidden (4*B*1024) ] f32.
// Workspace (158 MB): u_xt 32 | u_f 32 | u_r 32 | xbf 32 | Wt 24 | Aseg 2 | Bseg 2 | cstart 2.
extern "C" void kernel_launch(void* const* d_in, const int* in_sizes, int n_in,
                              void* d_out, int out_size, void* d_ws, size_t ws_size,
                              hipStream_t stream) {
    const int*   tok = (const int*)d_in[0];
    const float* emb = (const float*)d_in[2];
    const float* Ws  = (const float*)d_in[3];
    const float* bs  = (const float*)d_in[4];

    float* out    = (float*)d_out;
    float* x      = out;
    float* hidden = out + (size_t)NTOK * DIN;

    char* ws = (char*)d_ws;
    unsigned short* u_xt   = (unsigned short*)ws;                       // 32 MB
    unsigned short* u_f    = (unsigned short*)(ws + (32u  << 20));      // 32 MB
    unsigned short* u_r    = (unsigned short*)(ws + (64u  << 20));      // 32 MB
    unsigned short* xbf    = (unsigned short*)(ws + (96u  << 20));      // 32 MB
    unsigned short* Wt     = (unsigned short*)(ws + (128u << 20));      // 24 MB
    float*          Aseg   = (float*)(ws + (152u << 20));               // 2 MB
    float*          Bseg   = (float*)(ws + (154u << 20));               // 2 MB
    float*          cstart = (float*)(ws + (156u << 20));               // 2 MB

    transpose_w<<<dim3(NBIG / 32, DIN / 32, NLAYERS), 256, 0, stream>>>(Ws, Wt);
    embed_kernel<<<NTOK, 256, 0, stream>>>(tok, emb, x, xbf);

    const int scan_blocks4 = NCHAIN * SEG / 4 / 256;   // 512 (4 chains/thread)

    for (int l = 0; l < NLAYERS; l++) {
        const unsigned short* Wl = Wt + (size_t)l * NBIG * DIN;
        const float* b = bs + (size_t)l * 4 * NOUT;
        gemm_bf16<<<dim3(NBIG / 256, NTOK / 256), 512, 0, stream>>>(xbf, Wl, u_xt, u_f, u_r);
        scan_phaseA<<<scan_blocks4, 256, 0, stream>>>(u_xt, u_f, b, Aseg, Bseg);
        scan_phaseB<<<NCHAIN / 2 / 256, 256, 0, stream>>>(Aseg, Bseg, cstart,
                                                          hidden + (size_t)l * BATCH * DIN);
        scan_phaseC<<<scan_blocks4, 256, 0, stream>>>(u_xt, u_f, u_r, x, xbf, b, cstart,
                                                      l < NLAYERS - 1);
    }
}

// Round 7
// 886.413 us; speedup vs baseline: 1.3524x; 1.0241x over previous
//
#include <hip/hip_runtime.h>
#include <hip/hip_bf16.h>
#include <cmath>

// Problem constants
#define L_SEQ  1024
#define BATCH  16
#define NOUT   512          // n
#define DIN    1024         // 2n = layer input dim = GEMM K
#define NBIG   3072         // 6n = GEMM N
#define NLAYERS 4
#define NTOK   (L_SEQ * BATCH)   // 16384 = GEMM M
#define NCHAIN 16384             // B * 2 * n independent scan chains
#define SEG    32                // segments per chain
#define SEGLEN (L_SEQ / SEG)     // 32 steps per segment

typedef __attribute__((ext_vector_type(8))) short bf16x8;
typedef __attribute__((ext_vector_type(4))) float f32x4;

__device__ __forceinline__ unsigned short f2bf(float f) {
    unsigned x = __float_as_uint(f);
    unsigned r = (x + 0x7fffu + ((x >> 16) & 1u)) >> 16;   // RNE
    return (unsigned short)r;
}
__device__ __forceinline__ float bf2f(unsigned short hv) {
    return __uint_as_float((unsigned)hv << 16);
}
__device__ __forceinline__ float sigmf(float v) {
    return 1.f / (1.f + __expf(-v));
}
__device__ __forceinline__ void async16(const void* g, const void* l) {
    __builtin_amdgcn_global_load_lds(
        (const __attribute__((address_space(1))) unsigned int*)g,
        (__attribute__((address_space(3))) unsigned int*)l, 16, 0, 0);
}

// ---------------- W convert + transpose: W(1024,3072) f32 -> Wt(3072,1024) bf16 ----------------
__global__ __launch_bounds__(256)
void transpose_w(const float* __restrict__ Ws, unsigned short* __restrict__ Wt) {
    __shared__ float tile[32][33];
    int l = blockIdx.z;
    const float* W = Ws + (size_t)l * DIN * NBIG;
    unsigned short* Wo = Wt + (size_t)l * NBIG * DIN;
    int n0 = blockIdx.x * 32, k0 = blockIdx.y * 32;
    int tx = threadIdx.x & 31, ty = threadIdx.x >> 5;
    #pragma unroll
    for (int i = 0; i < 4; i++)
        tile[ty + 8 * i][tx] = W[(size_t)(k0 + ty + 8 * i) * NBIG + n0 + tx];
    __syncthreads();
    #pragma unroll
    for (int i = 0; i < 4; i++)
        Wo[(size_t)(n0 + ty + 8 * i) * DIN + k0 + tx] = f2bf(tile[tx][ty + 8 * i]);
}

// ---------------- embedding gather: write x fp32 + xbf bf16 ----------------
__global__ void embed_kernel(const int* __restrict__ tok,
                             const float* __restrict__ emb,
                             float* __restrict__ x,
                             unsigned short* __restrict__ xbf) {
    int t = blockIdx.x;
    int row = tok[t];
    float4 v = ((const float4*)(emb + (size_t)row * DIN))[threadIdx.x];
    ((float4*)(x + (size_t)t * DIN))[threadIdx.x] = v;
    ushort4 h;
    h.x = f2bf(v.x); h.y = f2bf(v.y); h.z = f2bf(v.z); h.w = f2bf(v.w);
    ((ushort4*)(xbf + (size_t)t * DIN))[threadIdx.x] = h;
}

// ---------------- bf16 MFMA GEMM: u = x @ W ----------------
// 256x256 tile, BK=64, 8 waves (2M x 4N), per-wave 128x64 output (8x4 frags).
// r3/r5-verified 8-phase schedule + dual-bg (B0 held in regs for P4/P8).
// r6-verified vectorized epilogue: acc -> ds_write Cbuf[256][256] bf16
// (feat ^ (quad<<4) swizzle, 2-way=free) -> bar -> 16x ds_read_b128 ->
// 16x coalesced dwordx4 stores. Measured: 111 us, MfmaUtil 38.5, WRITE 115MB.
// Stage slots: P1 B0(2t+1)->buf1 | P2 A0(2t+2) | P3 B1(2t+2) | P4 A1(2t+2)
//            | P5 B0(2t+2)->buf0 | P6 A0(2t+3) | P7 B1(2t+3) | P8 A1(2t+3).
// vmcnt(6) at P4/P8 only; region read at phase p is stage-safe at p+1.
// LDS chunk-XOR swizzle: chunk c of row r at slot c^(r&7); staged via
// source-side permutation (lane L: dest slot L&7, src chunk (L&7)^(L>>3)).

#define STAGE_A(b, mh, kt, src)                                             \
    do {                                                                    \
        _Pragma("unroll")                                                   \
        for (int q = 0; q < 2; q++) {                                       \
            int rbase = q * 128 + (mh) * 64 + w * 8;                        \
            async16((src) + (size_t)(rbase + sr) * DIN + (kt) * 64 + sc * 8,\
                    &lds[b][0][rbase * 64]);                                \
        }                                                                   \
    } while (0)

#define STAGE_B(b, nh, kt, src)                                             \
    do {                                                                    \
        _Pragma("unroll")                                                   \
        for (int q = 0; q < 2; q++) {                                       \
            int gi = q * 8 + w;                                             \
            int rbase = (gi >> 2) * 64 + (nh) * 32 + (gi & 3) * 8;          \
            async16((src) + (size_t)(rbase + sr) * DIN + (kt) * 64 + sc * 8,\
                    &lds[b][1][rbase * 64]);                                \
        }                                                                   \
    } while (0)

#define LOAD_A(b, mh)                                                       \
    do {                                                                    \
        _Pragma("unroll")                                                   \
        for (int i = 0; i < 4; i++) {                                       \
            int ra = wm * 128 + (mh) * 64 + i * 16 + l16;                   \
            _Pragma("unroll")                                               \
            for (int kk = 0; kk < 2; kk++) {                                \
                int slot = (kk * 4 + quad) ^ (ra & 7);                      \
                af[i][kk] = *(const bf16x8*)&lds[b][0][ra * 64 + slot * 8]; \
            }                                                               \
        }                                                                   \
    } while (0)

#define LOAD_B(b, nh)                                                       \
    do {                                                                    \
        _Pragma("unroll")                                                   \
        for (int j = 0; j < 2; j++) {                                       \
            int rb = wn * 64 + (nh) * 32 + j * 16 + l16;                    \
            _Pragma("unroll")                                               \
            for (int kk = 0; kk < 2; kk++) {                                \
                int slot = (kk * 4 + quad) ^ (rb & 7);                      \
                bg[nh][j][kk] = *(const bf16x8*)&lds[b][1][rb * 64 + slot * 8]; \
            }                                                               \
        }                                                                   \
    } while (0)

#define MMA(mh, nh)                                                         \
    do {                                                                    \
        __builtin_amdgcn_s_setprio(1);                                      \
        _Pragma("unroll")                                                   \
        for (int i = 0; i < 4; i++)                                         \
            _Pragma("unroll")                                               \
            for (int j = 0; j < 2; j++)                                     \
                _Pragma("unroll")                                           \
                for (int kk = 0; kk < 2; kk++)                              \
                    acc[(mh) * 4 + i][(nh) * 2 + j] =                       \
                        __builtin_amdgcn_mfma_f32_16x16x32_bf16(            \
                            af[i][kk], bg[nh][j][kk],                       \
                            acc[(mh) * 4 + i][(nh) * 2 + j], 0, 0, 0);      \
        __builtin_amdgcn_s_setprio(0);                                      \
    } while (0)

#define BAR()   __builtin_amdgcn_s_barrier()
#define LGKM0() do { asm volatile("s_waitcnt lgkmcnt(0)" ::: "memory");     \
                     __builtin_amdgcn_sched_barrier(0); } while (0)
#define LGKM8() asm volatile("s_waitcnt lgkmcnt(8)" ::: "memory")
#define VM6()   asm volatile("s_waitcnt vmcnt(6)" ::: "memory")
#define VM0()   asm volatile("s_waitcnt vmcnt(0)" ::: "memory")

__global__ __launch_bounds__(512)
void gemm_bf16(const unsigned short* __restrict__ Abf,
               const unsigned short* __restrict__ Bt,
               unsigned short* __restrict__ u_xt,
               unsigned short* __restrict__ u_f,
               unsigned short* __restrict__ u_r) {
    __shared__ __align__(16) unsigned short lds[2][2][256 * 64];  // 128 KiB
    unsigned short* Cbuf = &lds[0][0][0];                         // epilogue alias

    const int tid  = threadIdx.x;
    const int lane = tid & 63;
    const int w    = tid >> 6;          // wave 0..7
    const int wm   = w >> 2, wn = w & 3;
    const int quad = lane >> 4, l16 = lane & 15;

    // XCD-aware bijective swizzle: grid 12x64 = 768 blocks, 768 % 8 == 0.
    const int flat = blockIdx.y * (NBIG / 256) + blockIdx.x;
    const int swz  = (flat & 7) * (NTOK / 256 * NBIG / 256 / 8) + (flat >> 3);
    const int M0 = (swz / (NBIG / 256)) * 256;
    const int N0 = (swz % (NBIG / 256)) * 256;

    const unsigned short* Asrc = Abf + (size_t)M0 * DIN;
    const unsigned short* Bsrc = Bt  + (size_t)N0 * DIN;

    // Output plane: each 256-wide N-tile lies in exactly one plane+dir.
    const int dir   = N0 >= 3 * NOUT;
    const int jj0   = N0 - dir * 3 * NOUT;
    const int plane = jj0 >> 9;
    unsigned short* pl = (plane == 0 ? u_xt : plane == 1 ? u_f : u_r)
                         + dir * NOUT + (jj0 & 511);

    f32x4 acc[8][4];
    #pragma unroll
    for (int i = 0; i < 8; i++)
        #pragma unroll
        for (int j = 0; j < 4; j++)
            acc[i][j] = (f32x4){0.f, 0.f, 0.f, 0.f};

    // staging lane coords (8-row groups, 8 chunks/row)
    const int sr = lane >> 3;           // row within group 0..7
    const int sc = (lane & 7) ^ sr;     // source k-chunk (swizzle inverse)

    bf16x8 af[4][2], bg[2][2][2];

    // Prologue: tile0 (all 4 stripes) -> buf0; tile1 {A0,B1,A1} -> buf1.
    STAGE_A(0, 0, 0, Asrc); STAGE_B(0, 0, 0, Bsrc);
    STAGE_B(0, 1, 0, Bsrc); STAGE_A(0, 1, 0, Asrc);
    STAGE_A(1, 0, 1, Asrc); STAGE_B(1, 1, 1, Bsrc); STAGE_A(1, 1, 1, Asrc);
    VM6();
    BAR();

    const int NITER = DIN / 128;        // 8 iterations x 2 K-tiles
    for (int t = 0; t < NITER; t++) {
        const int k1 = 2 * t + 1;
        const bool more = (t < NITER - 1);

        // ---- K-tile 2t from buf0 ----
        LOAD_A(0, 0); LOAD_B(0, 0);
        STAGE_B(1, 0, k1, Bsrc);
        LGKM8(); BAR(); LGKM0(); MMA(0, 0); BAR();
        LOAD_B(0, 1);
        if (more) STAGE_A(0, 0, k1 + 1, Asrc);
        BAR(); LGKM0(); MMA(0, 1); BAR();
        LOAD_A(0, 1);
        if (more) STAGE_B(0, 1, k1 + 1, Bsrc);
        BAR(); LGKM0(); MMA(1, 1); BAR();
        if (more) { STAGE_A(0, 1, k1 + 1, Asrc); VM6(); }
        else      { VM0(); }
        BAR(); MMA(1, 0); BAR();

        // ---- K-tile 2t+1 from buf1 ----
        LOAD_A(1, 0); LOAD_B(1, 0);
        if (more) STAGE_B(0, 0, k1 + 1, Bsrc);
        LGKM8(); BAR(); LGKM0(); MMA(0, 0); BAR();
        LOAD_B(1, 1);
        if (more) STAGE_A(1, 0, k1 + 2, Asrc);
        BAR(); LGKM0(); MMA(0, 1); BAR();
        LOAD_A(1, 1);
        if (more) STAGE_B(1, 1, k1 + 2, Bsrc);
        BAR(); LGKM0(); MMA(1, 1); BAR();
        if (more) { STAGE_A(1, 1, k1 + 2, Asrc); VM6(); }
        BAR(); MMA(1, 0); BAR();
    }

    // ---- Vectorized epilogue (LDS transpose; all loads drained by VM0) ----
    #pragma unroll
    for (int i = 0; i < 8; i++)
        #pragma unroll
        for (int j = 0; j < 4; j++)
            #pragma unroll
            for (int r = 0; r < 4; r++) {
                int row = wm * 128 + i * 16 + quad * 4 + r;
                int ft  = (wn * 64 + j * 16 + l16) ^ (quad << 4);
                Cbuf[row * 256 + ft] = f2bf(acc[i][j][r]);
            }
    asm volatile("s_waitcnt lgkmcnt(0)" ::: "memory");
    BAR();
    bf16x8 ctmp[16];
    #pragma unroll
    for (int ps = 0; ps < 16; ps++) {
        int cg = ps * 512 + tid; int row = cg >> 5; int c0 = cg & 31;
        int st = row * 256 + ((c0 << 3) ^ (((row >> 2) & 3) << 4));
        ctmp[ps] = *(const bf16x8*)&Cbuf[st];
    }
    LGKM0();
    #pragma unroll
    for (int ps = 0; ps < 16; ps++) {
        int cg = ps * 512 + tid; int row = cg >> 5; int c0 = cg & 31;
        *(bf16x8*)(pl + (size_t)(M0 + row) * DIN + c0 * 8) = ctmp[ps];
    }
}

// ---------------- chunked SRU scan ----------------
// chain = b*1024 + d*512 + i  (0..16383); element index at time t: t*16384 + chain.
// Segment s: steps j=0..31 at t = t0 + sgn*j; d=0: t0=s*32,sgn=+1; d=1: t0=1023-s*32,sgn=-1.
// Vectorized 2 chains/thread (r5-verified best point: 4 waves/SIMD TLP vs
// 8B/lane loads; 4-chain @ 2 waves/SIMD regressed 40us in r6).

// Phase A: per (chain-pair, seg) compute A=prod f, B=scan-from-0 result.
__global__ __launch_bounds__(256)
void scan_phaseA(const unsigned short* __restrict__ u_xt, const unsigned short* __restrict__ u_f,
                 const float* __restrict__ bias,
                 float* __restrict__ Aseg, float* __restrict__ Bseg) {
    int hgl = blockIdx.x * 256 + threadIdx.x;   // s*8192 + chain/2
    int c2 = hgl & (NCHAIN / 2 - 1);
    int s = hgl >> 13;
    int chain = c2 * 2;
    int rest = chain & 1023;                    // d*512 + i  (even)
    float bf0 = bias[rest], bf1 = bias[rest + 1];

    int d = rest >> 9;
    int t0 = d ? (L_SEQ - 1 - s * SEGLEN) : (s * SEGLEN);
    int sgn = d ? -1 : 1;
    long long idx = (long long)t0 * NCHAIN + chain;
    long long step = (long long)sgn * NCHAIN;

    float c0 = 0.f, A0 = 1.f, c1 = 0.f, A1 = 1.f;
    #pragma unroll 8
    for (int j = 0; j < SEGLEN; j++) {
        unsigned xt2 = *(const unsigned*)(u_xt + idx);
        unsigned f2v = *(const unsigned*)(u_f + idx);
        float xt0 = bf2f((unsigned short)xt2), xt1 = bf2f((unsigned short)(xt2 >> 16));
        float f0 = sigmf(bf2f((unsigned short)f2v) + bf0);
        float f1 = sigmf(bf2f((unsigned short)(f2v >> 16)) + bf1);
        c0 = f0 * c0 + (1.f - f0) * xt0;  A0 *= f0;
        c1 = f1 * c1 + (1.f - f1) * xt1;  A1 *= f1;
        idx += step;
    }
    int g = s * NCHAIN + chain;
    *(float2*)(Aseg + g) = make_float2(A0, A1);
    *(float2*)(Bseg + g) = make_float2(c0, c1);
}

// Phase B: compose segment carries per chain (2 chains/thread); write cstart
// per segment and the final c (== hidden state, layout (B,2n) flat == chain).
__global__ __launch_bounds__(256)
void scan_phaseB(const float* __restrict__ Aseg, const float* __restrict__ Bseg,
                 float* __restrict__ cstart, float* __restrict__ c_out) {
    int c2 = (blockIdx.x * 256 + threadIdx.x) * 2;
    float cx = 0.f, cy = 0.f;
    #pragma unroll
    for (int s = 0; s < SEG; s++) {
        int g = s * NCHAIN + c2;
        float2 A = *(const float2*)(Aseg + g);
        float2 B = *(const float2*)(Bseg + g);
        *(float2*)(cstart + g) = make_float2(cx, cy);
        cx = A.x * cx + B.x;
        cy = A.y * cy + B.y;
    }
    *(float2*)(c_out + c2) = make_float2(cx, cy);
}

// Phase C: re-scan each segment from true cstart, emit h (in-place on x) + bf16 copy.
__global__ __launch_bounds__(256)
void scan_phaseC(const unsigned short* __restrict__ u_xt, const unsigned short* __restrict__ u_f,
                 const unsigned short* __restrict__ u_r,
                 float* __restrict__ x, unsigned short* __restrict__ xbf,
                 const float* __restrict__ bias, const float* __restrict__ cstart,
                 int write_bf) {
    int hgl = blockIdx.x * 256 + threadIdx.x;   // s*8192 + chain/2
    int c2 = hgl & (NCHAIN / 2 - 1);
    int s = hgl >> 13;
    int chain = c2 * 2;
    int rest = chain & 1023;
    float bf0 = bias[rest],        bf1 = bias[rest + 1];
    float br0 = bias[1024 + rest], br1 = bias[1024 + rest + 1];

    int d = rest >> 9;
    int t0 = d ? (L_SEQ - 1 - s * SEGLEN) : (s * SEGLEN);
    int sgn = d ? -1 : 1;
    long long idx = (long long)t0 * NCHAIN + chain;
    long long step = (long long)sgn * NCHAIN;

    float2 cs = *(const float2*)(cstart + (size_t)s * NCHAIN + chain);
    float c0 = cs.x, c1 = cs.y;
    #pragma unroll 4
    for (int j = 0; j < SEGLEN; j++) {
        unsigned xt2 = *(const unsigned*)(u_xt + idx);
        unsigned f2v = *(const unsigned*)(u_f + idx);
        unsigned r2v = *(const unsigned*)(u_r + idx);
        float2 xp = *(const float2*)(x + idx);
        float f0 = sigmf(bf2f((unsigned short)f2v) + bf0);
        float f1 = sigmf(bf2f((unsigned short)(f2v >> 16)) + bf1);
        float r0 = sigmf(bf2f((unsigned short)r2v) + br0);
        float r1 = sigmf(bf2f((unsigned short)(r2v >> 16)) + br1);
        c0 = f0 * c0 + (1.f - f0) * bf2f((unsigned short)xt2);
        c1 = f1 * c1 + (1.f - f1) * bf2f((unsigned short)(xt2 >> 16));
        float th0 = 1.f - 2.f / (__expf(2.f * c0) + 1.f);
        float th1 = 1.f - 2.f / (__expf(2.f * c1) + 1.f);
        float h0 = r0 * th0 + (1.f - r0) * xp.x;
        float h1 = r1 * th1 + (1.f - r1) * xp.y;
        *(float2*)(x + idx) = make_float2(h0, h1);
        if (write_bf)
            *(unsigned*)(xbf + idx) = (unsigned)f2bf(h0) | ((unsigned)f2bf(h1) << 16);
        idx += step;
    }
}

// ---------------- launch ----------------
// d_out: [ x (L*B*1024) | hidden (4*B*1024) ] f32.
// Workspace (158 MB): u_xt 32 | u_f 32 | u_r 32 | xbf 32 | Wt 24 | Aseg 2 | Bseg 2 | cstart 2.
extern "C" void kernel_launch(void* const* d_in, const int* in_sizes, int n_in,
                              void* d_out, int out_size, void* d_ws, size_t ws_size,
                              hipStream_t stream) {
    const int*   tok = (const int*)d_in[0];
    const float* emb = (const float*)d_in[2];
    const float* Ws  = (const float*)d_in[3];
    const float* bs  = (const float*)d_in[4];

    float* out    = (float*)d_out;
    float* x      = out;
    float* hidden = out + (size_t)NTOK * DIN;

    char* ws = (char*)d_ws;
    unsigned short* u_xt   = (unsigned short*)ws;                       // 32 MB
    unsigned short* u_f    = (unsigned short*)(ws + (32u  << 20));      // 32 MB
    unsigned short* u_r    = (unsigned short*)(ws + (64u  << 20));      // 32 MB
    unsigned short* xbf    = (unsigned short*)(ws + (96u  << 20));      // 32 MB
    unsigned short* Wt     = (unsigned short*)(ws + (128u << 20));      // 24 MB
    float*          Aseg   = (float*)(ws + (152u << 20));               // 2 MB
    float*          Bseg   = (float*)(ws + (154u << 20));               // 2 MB
    float*          cstart = (float*)(ws + (156u << 20));               // 2 MB

    transpose_w<<<dim3(NBIG / 32, DIN / 32, NLAYERS), 256, 0, stream>>>(Ws, Wt);
    embed_kernel<<<NTOK, 256, 0, stream>>>(tok, emb, x, xbf);

    const int scan_blocks2 = NCHAIN * SEG / 2 / 256;   // 1024 (2 chains/thread)

    for (int l = 0; l < NLAYERS; l++) {
        const unsigned short* Wl = Wt + (size_t)l * NBIG * DIN;
        const float* b = bs + (size_t)l * 4 * NOUT;
        gemm_bf16<<<dim3(NBIG / 256, NTOK / 256), 512, 0, stream>>>(xbf, Wl, u_xt, u_f, u_r);
        scan_phaseA<<<scan_blocks2, 256, 0, stream>>>(u_xt, u_f, b, Aseg, Bseg);
        scan_phaseB<<<NCHAIN / 2 / 256, 256, 0, stream>>>(Aseg, Bseg, cstart,
                                                          hidden + (size_t)l * BATCH * DIN);
        scan_phaseC<<<scan_blocks2, 256, 0, stream>>>(u_xt, u_f, u_r, x, xbf, b, cstart,
                                                      l < NLAYERS - 1);
    }
}